// Round 11
// baseline (344.922 us; speedup 1.0000x reference)
//
#include <hip/hip_runtime.h>
#include <hip/hip_bf16.h>

typedef unsigned short u16;
typedef short s16x8 __attribute__((ext_vector_type(8)));
typedef float f32x4 __attribute__((ext_vector_type(4)));

#define MFMA_BF16(a, b, c) __builtin_amdgcn_mfma_f32_16x16x32_bf16((a), (b), (c), 0, 0, 0)

static constexpr int D_IN   = 64;
static constexpr int H_DIM  = 512;
static constexpr int M_TILE = 64;
static constexpr int AST    = 520;  // LDS row stride (bf16): b128 A-reads conflict-free
static constexpr int XST    = 72;   // LDS row stride for x tile

__device__ __forceinline__ u16 f2bf(float f) {
  unsigned u = __builtin_bit_cast(unsigned, f);
  u += 0x7fffu + ((u >> 16) & 1u);   // RNE
  return (u16)(u >> 16);
}
__device__ __forceinline__ float bfb2f(unsigned bits16) {
  return __builtin_bit_cast(float, bits16 << 16);
}
__device__ __forceinline__ float fast_tanh(float x) {
  float e = __expf(2.0f * x);
  return 1.0f - 2.0f * __builtin_amdgcn_rcpf(e + 1.0f);
}

// LDS-only barrier (round-10, kept: -2.5us vs __syncthreads).
__device__ __forceinline__ void block_sync_lds() {
  asm volatile("s_waitcnt lgkmcnt(0)" ::: "memory");
  __builtin_amdgcn_s_barrier();
  asm volatile("" ::: "memory");
}

// ---- prep: fp32 weights -> bf16, packed in MFMA-B-fragment order ----
// (unchanged from rounds 0/6/10)
__global__ __launch_bounds__(256) void prep_weights(const float* __restrict__ W0,
                                                    const float* __restrict__ W1,
                                                    const float* __restrict__ W2,
                                                    u16* __restrict__ ws) {
  u16* p0f = ws;                       // fwd W0: K=64,  N=512
  u16* p0b = p0f + D_IN * H_DIM;       // bwd W0^T: K=512, N=64
  u16* p1f = p0b + D_IN * H_DIM;
  u16* p1b = p1f + H_DIM * H_DIM;
  u16* p2f = p1b + H_DIM * H_DIM;
  u16* p2b = p2f + H_DIM * H_DIM;

  __shared__ __align__(16) u16 tile[64 * 72];   // 9.0 KB

  int b = blockIdx.x;
  const float* src;
  u16 *dstf, *dstb;
  int rb, cb;
  bool isW0;
  if (b < 64) {
    src = W1; dstf = p1f; dstb = p1b; rb = b >> 3; cb = b & 7; isW0 = false;
  } else if (b < 128) {
    src = W2; dstf = p2f; dstb = p2b; rb = (b - 64) >> 3; cb = (b - 64) & 7; isW0 = false;
  } else {
    src = W0; dstf = p0f; dstb = p0b; rb = 0; cb = b - 128; isW0 = true;
  }

  const int tid = threadIdx.x;

  {
    int r = tid >> 2, cc = (tid & 3) * 16;
    const float4* s4 = (const float4*)(src + (size_t)(rb * 64 + r) * 512 + cb * 64 + cc);
    unsigned pk[8];
    #pragma unroll
    for (int v = 0; v < 4; ++v) {
      float4 f = s4[v];
      pk[v * 2]     = (unsigned)f2bf(f.x) | ((unsigned)f2bf(f.y) << 16);
      pk[v * 2 + 1] = (unsigned)f2bf(f.z) | ((unsigned)f2bf(f.w) << 16);
    }
    uint4* d = (uint4*)(tile + r * 72 + cc);
    d[0] = make_uint4(pk[0], pk[1], pk[2], pk[3]);
    d[1] = make_uint4(pk[4], pk[5], pk[6], pk[7]);
  }
  __syncthreads();

  const int c   = tid >> 6;
  const int kcl = (tid >> 5) & 1;
  const int ls  = (tid * 2) & 63;
  const int q   = ls >> 4;
  const int ln  = ls & 15;

  {
    __align__(16) u16 o[16];
    #pragma unroll
    for (int half = 0; half < 2; ++half)
      #pragma unroll
      for (int j = 0; j < 8; ++j)
        o[half * 8 + j] = tile[(kcl * 32 + q * 8 + j) * 72 + c * 16 + ln + half];
    int ntg   = 4 * cb + c;
    int kc    = 2 * rb + kcl;
    int chunk = isW0 ? (ntg * 2 + kc) : (ntg * 16 + kc);
    u16* dp = dstf + ((size_t)chunk * 64 + ls) * 8;
    *(uint4*)dp       = *(const uint4*)o;
    *(uint4*)(dp + 8) = *(const uint4*)(o + 8);
  }

  {
    const u16* rp = tile + (c * 16 + ln) * 72 + kcl * 32 + q * 8;
    s16x8 r0 = *(const s16x8*)rp;
    s16x8 r1 = *(const s16x8*)(rp + 72);
    int ntg = 4 * rb + c;
    int kc  = 2 * cb + kcl;
    u16* dp = dstb + ((size_t)(ntg * 16 + kc) * 64 + ls) * 8;
    *(s16x8*)dp       = r0;
    *(s16x8*)(dp + 8) = r1;
  }
}

// Load this wave's 4 B-tiles of k-chunk KC straight into VGPRs (BR[4]).
#define LOAD_B4(BP, KC, BR)                                                     \
  {                                                                             \
    const u16* _sr = (BP) + ((size_t)wave << 15) + ((KC) << 9) + lane * 8;      \
    _Pragma("unroll")                                                           \
    for (int s = 0; s < 4; ++s)                                                 \
      (BR)[s] = *(const s16x8*)(_sr + (s << 13));                               \
  }

// 512-wide GEMM K-loop: wave = 64 rows x 64 cols. A from LDS buffer RB
// (b128, conflict-free); B all-register, 2-deep dbuf.
// Wave-group skew: waves 0-3 (one per SIMD; wave i pairs with i+4 on SIMD i)
// raise priority for the K-loop. The prioritized wave drains its MFMA early
// and runs its VALU epilogue while the paired wave still issues MFMA ->
// cross-wave MFMA/VALU overlap inside each barrier segment (T5 with the
// role-asymmetry it needs; symmetric waves made it null, m190/m191).
#define GEMM512_REG(BP, RB)                                                     \
  {                                                                             \
    if (wlo) __builtin_amdgcn_s_setprio(1);                                     \
    _Pragma("unroll") for (int mt = 0; mt < 4; ++mt)                            \
      _Pragma("unroll") for (int nt = 0; nt < 4; ++nt)                          \
        acc[mt][nt] = (f32x4){0.f, 0.f, 0.f, 0.f};                              \
    for (int kc2 = 0; kc2 < 8; ++kc2) {                                         \
      const int e = kc2 * 2;                                                    \
      {                                                                         \
        s16x8 a[4];                                                             \
        _Pragma("unroll")                                                       \
        for (int mt = 0; mt < 4; ++mt)                                          \
          a[mt] = *(const s16x8*)((RB) + (mt * 16 + ln) * AST + e * 32 + q * 8);\
        _Pragma("unroll")                                                       \
        for (int nt = 0; nt < 4; ++nt)                                          \
          _Pragma("unroll")                                                     \
          for (int mt = 0; mt < 4; ++mt)                                        \
            acc[mt][nt] = MFMA_BF16(a[mt], bregA[nt], acc[mt][nt]);             \
        if (kc2 < 7) LOAD_B4(BP, e + 2, bregA);                                 \
      }                                                                         \
      const int o = e + 1;                                                      \
      {                                                                         \
        s16x8 a[4];                                                             \
        _Pragma("unroll")                                                       \
        for (int mt = 0; mt < 4; ++mt)                                          \
          a[mt] = *(const s16x8*)((RB) + (mt * 16 + ln) * AST + o * 32 + q * 8);\
        _Pragma("unroll")                                                       \
        for (int nt = 0; nt < 4; ++nt)                                          \
          _Pragma("unroll")                                                     \
          for (int mt = 0; mt < 4; ++mt)                                        \
            acc[mt][nt] = MFMA_BF16(a[mt], bregB[nt], acc[mt][nt]);             \
        if (kc2 < 7) LOAD_B4(BP, o + 2, bregB);                                 \
      }                                                                         \
    }                                                                           \
    if (wlo) __builtin_amdgcn_s_setprio(0);                                     \
  }

// block=512 (8 waves), wave = 64x64 slice. Ping-pong activation LDS,
// lgkmcnt-only barriers (round-10 best, 159.7us), + wave-group setprio skew.
__global__ __launch_bounds__(512, 2) void hnn_fused(
    const float* __restrict__ x,
    const float* __restrict__ bias0,
    const float* __restrict__ bias1,
    const float* __restrict__ bias2,
    const float* __restrict__ W3,
    const u16* __restrict__ ws,
    float* __restrict__ out)
{
  const u16* p0f = ws;
  const u16* p0b = p0f + D_IN * H_DIM;
  const u16* p1f = p0b + D_IN * H_DIM;
  const u16* p1b = p1f + H_DIM * H_DIM;
  const u16* p2f = p1b + H_DIM * H_DIM;
  const u16* p2b = p2f + H_DIM * H_DIM;

  __shared__ __align__(16) u16 xs[M_TILE * XST];     // 9.0 KB
  __shared__ __align__(16) u16 bufA[M_TILE * AST];   // 65.0 KB
  __shared__ __align__(16) u16 bufB[M_TILE * AST];   // 65.0 KB

  const int tid  = threadIdx.x;
  const int wave = tid >> 6;      // 0..7
  const int lane = tid & 63;
  const int ln   = lane & 15;
  const int q    = lane >> 4;
  const int nwb  = wave * 64;     // wave's 64-col slice
  const int row0 = blockIdx.x * M_TILE;
  const bool wlo = wave < 4;      // one prioritized wave per SIMD (pairs i, i+4)

  // ---- stage x tile: 64x64 fp32 -> bf16 LDS (512 thr x 8 elems) ----
  {
    int r = tid >> 3, c = (tid & 7) * 8;
    const float4* src = (const float4*)(x + (size_t)(row0 + r) * D_IN + c);
    float4 f0 = src[0];
    float4 f1 = src[1];
    u16* dst = xs + r * XST + c;
    dst[0] = f2bf(f0.x); dst[1] = f2bf(f0.y); dst[2] = f2bf(f0.z); dst[3] = f2bf(f0.w);
    dst[4] = f2bf(f1.x); dst[5] = f2bf(f1.y); dst[6] = f2bf(f1.z); dst[7] = f2bf(f1.w);
  }
  block_sync_lds();

  f32x4 acc[4][4];
  s16x8 bregA[4], bregB[4];   // register-B double buffer
  unsigned h0p[4][4][2];      // h0 bf16x2-packed, C-layout (for tanh' in bwd)
  unsigned h1p[4][4][2];
  float bias[4];

  // ================ GEMM0: z0 = x @ W0  (K=64, register-B) ================
  #pragma unroll
  for (int nt = 0; nt < 4; ++nt) bias[nt] = bias0[nwb + nt * 16 + ln];
  #pragma unroll
  for (int mt = 0; mt < 4; ++mt)
    #pragma unroll
    for (int nt = 0; nt < 4; ++nt) acc[mt][nt] = (f32x4){0.f, 0.f, 0.f, 0.f};
  {
    const u16* bpw0 = p0f + (wave << 12) + lane * 8;  // (wave*4 ntg) * 2 kc * 512
    #pragma unroll
    for (int kc = 0; kc < 2; ++kc) {
      s16x8 a[4];
      #pragma unroll
      for (int mt = 0; mt < 4; ++mt)
        a[mt] = *(const s16x8*)(xs + (mt * 16 + ln) * XST + kc * 32 + q * 8);
      #pragma unroll
      for (int nt = 0; nt < 4; ++nt) {
        s16x8 b = *(const s16x8*)(bpw0 + (nt << 10) + (kc << 9));
        #pragma unroll
        for (int mt = 0; mt < 4; ++mt)
          acc[mt][nt] = MFMA_BF16(a[mt], b, acc[mt][nt]);
      }
    }
  }
  LOAD_B4(p1f, 0, bregA);   // prefetch GEMM1 kc 0,1; overlaps epilogue VALU
  LOAD_B4(p1f, 1, bregB);
  // epi0: h0 = tanh(z0+b0) -> regs + bufA (first use)
  #pragma unroll
  for (int mt = 0; mt < 4; ++mt)
    #pragma unroll
    for (int nt = 0; nt < 4; ++nt) {
      int col = nwb + nt * 16 + ln;
      u16 u[4];
      #pragma unroll
      for (int r = 0; r < 4; ++r) {
        float th = fast_tanh(acc[mt][nt][r] + bias[nt]);
        u[r] = f2bf(th);
        bufA[(mt * 16 + q * 4 + r) * AST + col] = u[r];
      }
      h0p[mt][nt][0] = (unsigned)u[0] | ((unsigned)u[1] << 16);
      h0p[mt][nt][1] = (unsigned)u[2] | ((unsigned)u[3] << 16);
    }
  block_sync_lds();

  // ================ GEMM1: z1 = h0 @ W1  (reads A, writes B) ================
  #pragma unroll
  for (int nt = 0; nt < 4; ++nt) bias[nt] = bias1[nwb + nt * 16 + ln];
  GEMM512_REG(p1f, bufA);
  LOAD_B4(p2f, 0, bregA);   // prefetch GEMM2
  LOAD_B4(p2f, 1, bregB);
  #pragma unroll
  for (int mt = 0; mt < 4; ++mt)
    #pragma unroll
    for (int nt = 0; nt < 4; ++nt) {
      int col = nwb + nt * 16 + ln;
      u16 u[4];
      #pragma unroll
      for (int r = 0; r < 4; ++r) {
        float th = fast_tanh(acc[mt][nt][r] + bias[nt]);
        u[r] = f2bf(th);
        bufB[(mt * 16 + q * 4 + r) * AST + col] = u[r];
      }
      h1p[mt][nt][0] = (unsigned)u[0] | ((unsigned)u[1] << 16);
      h1p[mt][nt][1] = (unsigned)u[2] | ((unsigned)u[3] << 16);
    }
  block_sync_lds();

  // ================ GEMM2: z2 = h1 @ W2 ; gz2 = W3*(1-h2^2)  (reads B, writes A) ====
  #pragma unroll
  for (int nt = 0; nt < 4; ++nt) bias[nt] = bias2[nwb + nt * 16 + ln];
  float w3v[4];
  #pragma unroll
  for (int nt = 0; nt < 4; ++nt) w3v[nt] = W3[nwb + nt * 16 + ln];
  GEMM512_REG(p2f, bufB);
  LOAD_B4(p2b, 0, bregA);   // prefetch GEMM3
  LOAD_B4(p2b, 1, bregB);
  #pragma unroll
  for (int mt = 0; mt < 4; ++mt)
    #pragma unroll
    for (int nt = 0; nt < 4; ++nt) {
      int col = nwb + nt * 16 + ln;
      #pragma unroll
      for (int r = 0; r < 4; ++r) {
        float th = fast_tanh(acc[mt][nt][r] + bias[nt]);
        float gz = w3v[nt] * (1.0f - th * th);
        bufA[(mt * 16 + q * 4 + r) * AST + col] = f2bf(gz);
      }
    }
  block_sync_lds();

  // ================ GEMM3: g1 = gz2 @ W2^T ; gz1 = g1*(1-h1^2)  (reads A, writes B) ==
  GEMM512_REG(p2b, bufA);
  LOAD_B4(p1b, 0, bregA);   // prefetch GEMM4
  LOAD_B4(p1b, 1, bregB);
  #pragma unroll
  for (int mt = 0; mt < 4; ++mt)
    #pragma unroll
    for (int nt = 0; nt < 4; ++nt) {
      int col = nwb + nt * 16 + ln;
      unsigned pa = h1p[mt][nt][0], pb = h1p[mt][nt][1];
      float hh[4] = { bfb2f(pa & 0xffffu), bfb2f(pa >> 16),
                      bfb2f(pb & 0xffffu), bfb2f(pb >> 16) };
      #pragma unroll
      for (int r = 0; r < 4; ++r) {
        float gz = acc[mt][nt][r] * (1.0f - hh[r] * hh[r]);
        bufB[(mt * 16 + q * 4 + r) * AST + col] = f2bf(gz);
      }
    }
  block_sync_lds();

  // ================ GEMM4: g0 = gz1 @ W1^T ; gz0 = g0*(1-h0^2)  (reads B, writes A) ==
  // No barrier between GEMM4 and epi4 (ping-pong ordering, round-10).
  GEMM512_REG(p1b, bufB);
  #pragma unroll
  for (int mt = 0; mt < 4; ++mt)
    #pragma unroll
    for (int nt = 0; nt < 4; ++nt) {
      int col = nwb + nt * 16 + ln;
      unsigned pa = h0p[mt][nt][0], pb = h0p[mt][nt][1];
      float hh[4] = { bfb2f(pa & 0xffffu), bfb2f(pa >> 16),
                      bfb2f(pb & 0xffffu), bfb2f(pb >> 16) };
      #pragma unroll
      for (int r = 0; r < 4; ++r) {
        float gz = acc[mt][nt][r] * (1.0f - hh[r] * hh[r]);
        bufA[(mt * 16 + q * 4 + r) * AST + col] = f2bf(gz);
      }
    }
  block_sync_lds();

  // ================ GEMM5: gradH = gz0 @ W0^T (64x64), symplectic store ======
  {
    f32x4 acc5[2];
    acc5[0] = (f32x4){0.f, 0.f, 0.f, 0.f};
    acc5[1] = (f32x4){0.f, 0.f, 0.f, 0.f};
    const int mt5 = wave & 3;                  // row tile 0..3
    const int nb5 = (wave >> 2) * 32;          // gradH column base (0 or 32)
    const u16* bp5 = p0b + ((wave >> 2) << 14) + lane * 8;  // ntg5*16kc*512
    if (wlo) __builtin_amdgcn_s_setprio(1);
    #pragma unroll 2
    for (int kc = 0; kc < 16; ++kc) {
      s16x8 a = *(const s16x8*)(bufA + (mt5 * 16 + ln) * AST + kc * 32 + q * 8);
      #pragma unroll
      for (int nt = 0; nt < 2; ++nt) {
        s16x8 b = *(const s16x8*)(bp5 + (nt << 13) + (kc << 9));
        acc5[nt] = MFMA_BF16(a, b, acc5[nt]);
      }
    }
    if (wlo) __builtin_amdgcn_s_setprio(0);
    #pragma unroll
    for (int nt = 0; nt < 2; ++nt) {
      int g = nb5 + nt * 16 + ln;                 // gradH column
      int c = (g < 32) ? g + 32 : g - 32;         // out = concat(gradH[:,32:], -gradH[:,:32])
      float s = (g < 32) ? -1.0f : 1.0f;
      #pragma unroll
      for (int r = 0; r < 4; ++r) {
        int grow = row0 + mt5 * 16 + q * 4 + r;
        out[(size_t)grow * 64 + c] = s * acc5[nt][r];
      }
    }
  }
}

extern "C" void kernel_launch(void* const* d_in, const int* in_sizes, int n_in,
                              void* d_out, int out_size, void* d_ws, size_t ws_size,
                              hipStream_t stream) {
  // setup_inputs order: t, x, W0, b0, W1, b1, W2, b2, W3, b3
  const float* x  = (const float*)d_in[1];
  const float* W0 = (const float*)d_in[2];
  const float* b0 = (const float*)d_in[3];
  const float* W1 = (const float*)d_in[4];
  const float* b1 = (const float*)d_in[5];
  const float* W2 = (const float*)d_in[6];
  const float* b2 = (const float*)d_in[7];
  const float* W3 = (const float*)d_in[8];
  u16* ws = (u16*)d_ws;
  float* out = (float*)d_out;

  prep_weights<<<136, 256, 0, stream>>>(W0, W1, W2, ws);
  hnn_fused<<<65536 / M_TILE, 512, 0, stream>>>(x, b0, b1, b2, W3, ws, out);
}

// Round 12
// 228.758 us; speedup vs baseline: 1.5078x; 1.5078x over previous
//
#include <hip/hip_runtime.h>
#include <hip/hip_bf16.h>

typedef unsigned short u16;
typedef short s16x8 __attribute__((ext_vector_type(8)));
typedef float f32x4 __attribute__((ext_vector_type(4)));

#define MFMA_BF16(a, b, c) __builtin_amdgcn_mfma_f32_16x16x32_bf16((a), (b), (c), 0, 0, 0)

static constexpr int D_IN   = 64;
static constexpr int H_DIM  = 512;
static constexpr int M_TILE = 64;
static constexpr int AST    = 520;  // LDS row stride (bf16): b128 A-reads conflict-free
static constexpr int XST    = 72;   // LDS row stride for x tile

__device__ __forceinline__ u16 f2bf(float f) {
  unsigned u = __builtin_bit_cast(unsigned, f);
  u += 0x7fffu + ((u >> 16) & 1u);   // RNE
  return (u16)(u >> 16);
}
__device__ __forceinline__ float bfb2f(unsigned bits16) {
  return __builtin_bit_cast(float, bits16 << 16);
}
__device__ __forceinline__ float fast_tanh(float x) {
  float e = __expf(2.0f * x);
  return 1.0f - 2.0f * __builtin_amdgcn_rcpf(e + 1.0f);
}

// LDS-only barrier (round-10, kept: -2.5us vs __syncthreads).
__device__ __forceinline__ void block_sync_lds() {
  asm volatile("s_waitcnt lgkmcnt(0)" ::: "memory");
  __builtin_amdgcn_s_barrier();
  asm volatile("" ::: "memory");
}

// ---- prep: fp32 weights -> bf16, packed in MFMA-B-fragment order ----
// (unchanged from rounds 0/6/10)
__global__ __launch_bounds__(256) void prep_weights(const float* __restrict__ W0,
                                                    const float* __restrict__ W1,
                                                    const float* __restrict__ W2,
                                                    u16* __restrict__ ws) {
  u16* p0f = ws;                       // fwd W0: K=64,  N=512
  u16* p0b = p0f + D_IN * H_DIM;       // bwd W0^T: K=512, N=64
  u16* p1f = p0b + D_IN * H_DIM;
  u16* p1b = p1f + H_DIM * H_DIM;
  u16* p2f = p1b + H_DIM * H_DIM;
  u16* p2b = p2f + H_DIM * H_DIM;

  __shared__ __align__(16) u16 tile[64 * 72];   // 9.0 KB

  int b = blockIdx.x;
  const float* src;
  u16 *dstf, *dstb;
  int rb, cb;
  bool isW0;
  if (b < 64) {
    src = W1; dstf = p1f; dstb = p1b; rb = b >> 3; cb = b & 7; isW0 = false;
  } else if (b < 128) {
    src = W2; dstf = p2f; dstb = p2b; rb = (b - 64) >> 3; cb = (b - 64) & 7; isW0 = false;
  } else {
    src = W0; dstf = p0f; dstb = p0b; rb = 0; cb = b - 128; isW0 = true;
  }

  const int tid = threadIdx.x;

  {
    int r = tid >> 2, cc = (tid & 3) * 16;
    const float4* s4 = (const float4*)(src + (size_t)(rb * 64 + r) * 512 + cb * 64 + cc);
    unsigned pk[8];
    #pragma unroll
    for (int v = 0; v < 4; ++v) {
      float4 f = s4[v];
      pk[v * 2]     = (unsigned)f2bf(f.x) | ((unsigned)f2bf(f.y) << 16);
      pk[v * 2 + 1] = (unsigned)f2bf(f.z) | ((unsigned)f2bf(f.w) << 16);
    }
    uint4* d = (uint4*)(tile + r * 72 + cc);
    d[0] = make_uint4(pk[0], pk[1], pk[2], pk[3]);
    d[1] = make_uint4(pk[4], pk[5], pk[6], pk[7]);
  }
  __syncthreads();

  const int c   = tid >> 6;
  const int kcl = (tid >> 5) & 1;
  const int ls  = (tid * 2) & 63;
  const int q   = ls >> 4;
  const int ln  = ls & 15;

  {
    __align__(16) u16 o[16];
    #pragma unroll
    for (int half = 0; half < 2; ++half)
      #pragma unroll
      for (int j = 0; j < 8; ++j)
        o[half * 8 + j] = tile[(kcl * 32 + q * 8 + j) * 72 + c * 16 + ln + half];
    int ntg   = 4 * cb + c;
    int kc    = 2 * rb + kcl;
    int chunk = isW0 ? (ntg * 2 + kc) : (ntg * 16 + kc);
    u16* dp = dstf + ((size_t)chunk * 64 + ls) * 8;
    *(uint4*)dp       = *(const uint4*)o;
    *(uint4*)(dp + 8) = *(const uint4*)(o + 8);
  }

  {
    const u16* rp = tile + (c * 16 + ln) * 72 + kcl * 32 + q * 8;
    s16x8 r0 = *(const s16x8*)rp;
    s16x8 r1 = *(const s16x8*)(rp + 72);
    int ntg = 4 * rb + c;
    int kc  = 2 * cb + kcl;
    u16* dp = dstb + ((size_t)(ntg * 16 + kc) * 64 + ls) * 8;
    *(s16x8*)dp       = r0;
    *(s16x8*)(dp + 8) = r1;
  }
}

// Load this wave's 4 B-tiles of k-chunk KC straight into VGPRs (BR[4]).
#define LOAD_B4(BP, KC, BR)                                                     \
  {                                                                             \
    const u16* _sr = (BP) + ((size_t)wave << 15) + ((KC) << 9) + lane * 8;      \
    _Pragma("unroll")                                                           \
    for (int s = 0; s < 4; ++s)                                                 \
      (BR)[s] = *(const s16x8*)(_sr + (s << 13));                               \
  }

// 512-wide GEMM K-loop (round-10 structure): wave = 64 rows x 64 cols.
// A from LDS buffer RB (b128, conflict-free); B all-register, 2-deep dbuf.
// NO control flow inside (round-11 lesson: mid-loop branches tip the
// register cliff and spill).
#define GEMM512_REG(BP, RB)                                                     \
  {                                                                             \
    _Pragma("unroll") for (int mt = 0; mt < 4; ++mt)                            \
      _Pragma("unroll") for (int nt = 0; nt < 4; ++nt)                          \
        acc[mt][nt] = (f32x4){0.f, 0.f, 0.f, 0.f};                              \
    for (int kc2 = 0; kc2 < 8; ++kc2) {                                         \
      const int e = kc2 * 2;                                                    \
      {                                                                         \
        s16x8 a[4];                                                             \
        _Pragma("unroll")                                                       \
        for (int mt = 0; mt < 4; ++mt)                                          \
          a[mt] = *(const s16x8*)((RB) + (mt * 16 + ln) * AST + e * 32 + q * 8);\
        _Pragma("unroll")                                                       \
        for (int nt = 0; nt < 4; ++nt)                                          \
          _Pragma("unroll")                                                     \
          for (int mt = 0; mt < 4; ++mt)                                        \
            acc[mt][nt] = MFMA_BF16(a[mt], bregA[nt], acc[mt][nt]);             \
        if (kc2 < 7) LOAD_B4(BP, e + 2, bregA);                                 \
      }                                                                         \
      const int o = e + 1;                                                      \
      {                                                                         \
        s16x8 a[4];                                                             \
        _Pragma("unroll")                                                       \
        for (int mt = 0; mt < 4; ++mt)                                          \
          a[mt] = *(const s16x8*)((RB) + (mt * 16 + ln) * AST + o * 32 + q * 8);\
        _Pragma("unroll")                                                       \
        for (int nt = 0; nt < 4; ++nt)                                          \
          _Pragma("unroll")                                                     \
          for (int mt = 0; mt < 4; ++mt)                                        \
            acc[mt][nt] = MFMA_BF16(a[mt], bregB[nt], acc[mt][nt]);             \
        if (kc2 < 7) LOAD_B4(BP, o + 2, bregB);                                 \
      }                                                                         \
    }                                                                           \
  }

// block=512 (8 waves), wave = 64x64 slice. Round-10 structure (best, 159.7us)
// + ONE divergent statement at kernel entry: waves 0-3 (one per SIMD, paired
// with waves 4-7) run the whole kernel at priority 1. Within each barrier
// segment the prio wave drains its MFMA K-loop early and runs its VALU
// epilogue while the paired wave still issues MFMA (cross-wave pipe overlap);
// the low-prio wave issues whenever the high-prio wave stalls, so no
// starvation; barriers re-sync each segment. Codegen footprint ~4 insts at
// entry -- no perturbation of hot-loop regalloc (round-11's 12 branch sites
// caused spill and confounded the test).
__global__ __launch_bounds__(512, 2) void hnn_fused(
    const float* __restrict__ x,
    const float* __restrict__ bias0,
    const float* __restrict__ bias1,
    const float* __restrict__ bias2,
    const float* __restrict__ W3,
    const u16* __restrict__ ws,
    float* __restrict__ out)
{
  const u16* p0f = ws;
  const u16* p0b = p0f + D_IN * H_DIM;
  const u16* p1f = p0b + D_IN * H_DIM;
  const u16* p1b = p1f + H_DIM * H_DIM;
  const u16* p2f = p1b + H_DIM * H_DIM;
  const u16* p2b = p2f + H_DIM * H_DIM;

  __shared__ __align__(16) u16 xs[M_TILE * XST];     // 9.0 KB
  __shared__ __align__(16) u16 bufA[M_TILE * AST];   // 65.0 KB
  __shared__ __align__(16) u16 bufB[M_TILE * AST];   // 65.0 KB

  const int tid  = threadIdx.x;
  const int wave = tid >> 6;      // 0..7
  const int lane = tid & 63;
  const int ln   = lane & 15;
  const int q    = lane >> 4;
  const int nwb  = wave * 64;     // wave's 64-col slice
  const int row0 = blockIdx.x * M_TILE;

  // One prioritized wave per SIMD for the whole kernel (clean T5 test).
  if (wave < 4) __builtin_amdgcn_s_setprio(1);

  // ---- stage x tile: 64x64 fp32 -> bf16 LDS (512 thr x 8 elems) ----
  {
    int r = tid >> 3, c = (tid & 7) * 8;
    const float4* src = (const float4*)(x + (size_t)(row0 + r) * D_IN + c);
    float4 f0 = src[0];
    float4 f1 = src[1];
    u16* dst = xs + r * XST + c;
    dst[0] = f2bf(f0.x); dst[1] = f2bf(f0.y); dst[2] = f2bf(f0.z); dst[3] = f2bf(f0.w);
    dst[4] = f2bf(f1.x); dst[5] = f2bf(f1.y); dst[6] = f2bf(f1.z); dst[7] = f2bf(f1.w);
  }
  block_sync_lds();

  f32x4 acc[4][4];
  s16x8 bregA[4], bregB[4];   // register-B double buffer
  unsigned h0p[4][4][2];      // h0 bf16x2-packed, C-layout (for tanh' in bwd)
  unsigned h1p[4][4][2];
  float bias[4];

  // ================ GEMM0: z0 = x @ W0  (K=64, register-B) ================
  #pragma unroll
  for (int nt = 0; nt < 4; ++nt) bias[nt] = bias0[nwb + nt * 16 + ln];
  #pragma unroll
  for (int mt = 0; mt < 4; ++mt)
    #pragma unroll
    for (int nt = 0; nt < 4; ++nt) acc[mt][nt] = (f32x4){0.f, 0.f, 0.f, 0.f};
  {
    const u16* bpw0 = p0f + (wave << 12) + lane * 8;  // (wave*4 ntg) * 2 kc * 512
    #pragma unroll
    for (int kc = 0; kc < 2; ++kc) {
      s16x8 a[4];
      #pragma unroll
      for (int mt = 0; mt < 4; ++mt)
        a[mt] = *(const s16x8*)(xs + (mt * 16 + ln) * XST + kc * 32 + q * 8);
      #pragma unroll
      for (int nt = 0; nt < 4; ++nt) {
        s16x8 b = *(const s16x8*)(bpw0 + (nt << 10) + (kc << 9));
        #pragma unroll
        for (int mt = 0; mt < 4; ++mt)
          acc[mt][nt] = MFMA_BF16(a[mt], b, acc[mt][nt]);
      }
    }
  }
  LOAD_B4(p1f, 0, bregA);   // prefetch GEMM1 kc 0,1; overlaps epilogue VALU
  LOAD_B4(p1f, 1, bregB);
  // epi0: h0 = tanh(z0+b0) -> regs + bufA (first use)
  #pragma unroll
  for (int mt = 0; mt < 4; ++mt)
    #pragma unroll
    for (int nt = 0; nt < 4; ++nt) {
      int col = nwb + nt * 16 + ln;
      u16 u[4];
      #pragma unroll
      for (int r = 0; r < 4; ++r) {
        float th = fast_tanh(acc[mt][nt][r] + bias[nt]);
        u[r] = f2bf(th);
        bufA[(mt * 16 + q * 4 + r) * AST + col] = u[r];
      }
      h0p[mt][nt][0] = (unsigned)u[0] | ((unsigned)u[1] << 16);
      h0p[mt][nt][1] = (unsigned)u[2] | ((unsigned)u[3] << 16);
    }
  block_sync_lds();

  // ================ GEMM1: z1 = h0 @ W1  (reads A, writes B) ================
  #pragma unroll
  for (int nt = 0; nt < 4; ++nt) bias[nt] = bias1[nwb + nt * 16 + ln];
  GEMM512_REG(p1f, bufA);
  LOAD_B4(p2f, 0, bregA);   // prefetch GEMM2
  LOAD_B4(p2f, 1, bregB);
  #pragma unroll
  for (int mt = 0; mt < 4; ++mt)
    #pragma unroll
    for (int nt = 0; nt < 4; ++nt) {
      int col = nwb + nt * 16 + ln;
      u16 u[4];
      #pragma unroll
      for (int r = 0; r < 4; ++r) {
        float th = fast_tanh(acc[mt][nt][r] + bias[nt]);
        u[r] = f2bf(th);
        bufB[(mt * 16 + q * 4 + r) * AST + col] = u[r];
      }
      h1p[mt][nt][0] = (unsigned)u[0] | ((unsigned)u[1] << 16);
      h1p[mt][nt][1] = (unsigned)u[2] | ((unsigned)u[3] << 16);
    }
  block_sync_lds();

  // ================ GEMM2: z2 = h1 @ W2 ; gz2 = W3*(1-h2^2)  (reads B, writes A) ====
  #pragma unroll
  for (int nt = 0; nt < 4; ++nt) bias[nt] = bias2[nwb + nt * 16 + ln];
  float w3v[4];
  #pragma unroll
  for (int nt = 0; nt < 4; ++nt) w3v[nt] = W3[nwb + nt * 16 + ln];
  GEMM512_REG(p2f, bufB);
  LOAD_B4(p2b, 0, bregA);   // prefetch GEMM3
  LOAD_B4(p2b, 1, bregB);
  #pragma unroll
  for (int mt = 0; mt < 4; ++mt)
    #pragma unroll
    for (int nt = 0; nt < 4; ++nt) {
      int col = nwb + nt * 16 + ln;
      #pragma unroll
      for (int r = 0; r < 4; ++r) {
        float th = fast_tanh(acc[mt][nt][r] + bias[nt]);
        float gz = w3v[nt] * (1.0f - th * th);
        bufA[(mt * 16 + q * 4 + r) * AST + col] = f2bf(gz);
      }
    }
  block_sync_lds();

  // ================ GEMM3: g1 = gz2 @ W2^T ; gz1 = g1*(1-h1^2)  (reads A, writes B) ==
  GEMM512_REG(p2b, bufA);
  LOAD_B4(p1b, 0, bregA);   // prefetch GEMM4
  LOAD_B4(p1b, 1, bregB);
  #pragma unroll
  for (int mt = 0; mt < 4; ++mt)
    #pragma unroll
    for (int nt = 0; nt < 4; ++nt) {
      int col = nwb + nt * 16 + ln;
      unsigned pa = h1p[mt][nt][0], pb = h1p[mt][nt][1];
      float hh[4] = { bfb2f(pa & 0xffffu), bfb2f(pa >> 16),
                      bfb2f(pb & 0xffffu), bfb2f(pb >> 16) };
      #pragma unroll
      for (int r = 0; r < 4; ++r) {
        float gz = acc[mt][nt][r] * (1.0f - hh[r] * hh[r]);
        bufB[(mt * 16 + q * 4 + r) * AST + col] = f2bf(gz);
      }
    }
  block_sync_lds();

  // ================ GEMM4: g0 = gz1 @ W1^T ; gz0 = g0*(1-h0^2)  (reads B, writes A) ==
  // No barrier between GEMM4 and epi4 (ping-pong ordering, round-10).
  GEMM512_REG(p1b, bufB);
  #pragma unroll
  for (int mt = 0; mt < 4; ++mt)
    #pragma unroll
    for (int nt = 0; nt < 4; ++nt) {
      int col = nwb + nt * 16 + ln;
      unsigned pa = h0p[mt][nt][0], pb = h0p[mt][nt][1];
      float hh[4] = { bfb2f(pa & 0xffffu), bfb2f(pa >> 16),
                      bfb2f(pb & 0xffffu), bfb2f(pb >> 16) };
      #pragma unroll
      for (int r = 0; r < 4; ++r) {
        float gz = acc[mt][nt][r] * (1.0f - hh[r] * hh[r]);
        bufA[(mt * 16 + q * 4 + r) * AST + col] = f2bf(gz);
      }
    }
  block_sync_lds();

  // ================ GEMM5: gradH = gz0 @ W0^T (64x64), symplectic store ======
  {
    f32x4 acc5[2];
    acc5[0] = (f32x4){0.f, 0.f, 0.f, 0.f};
    acc5[1] = (f32x4){0.f, 0.f, 0.f, 0.f};
    const int mt5 = wave & 3;                  // row tile 0..3
    const int nb5 = (wave >> 2) * 32;          // gradH column base (0 or 32)
    const u16* bp5 = p0b + ((wave >> 2) << 14) + lane * 8;  // ntg5*16kc*512
    #pragma unroll 2
    for (int kc = 0; kc < 16; ++kc) {
      s16x8 a = *(const s16x8*)(bufA + (mt5 * 16 + ln) * AST + kc * 32 + q * 8);
      #pragma unroll
      for (int nt = 0; nt < 2; ++nt) {
        s16x8 b = *(const s16x8*)(bp5 + (nt << 13) + (kc << 9));
        acc5[nt] = MFMA_BF16(a, b, acc5[nt]);
      }
    }
    #pragma unroll
    for (int nt = 0; nt < 2; ++nt) {
      int g = nb5 + nt * 16 + ln;                 // gradH column
      int c = (g < 32) ? g + 32 : g - 32;         // out = concat(gradH[:,32:], -gradH[:,:32])
      float s = (g < 32) ? -1.0f : 1.0f;
      #pragma unroll
      for (int r = 0; r < 4; ++r) {
        int grow = row0 + mt5 * 16 + q * 4 + r;
        out[(size_t)grow * 64 + c] = s * acc5[nt][r];
      }
    }
  }
}

extern "C" void kernel_launch(void* const* d_in, const int* in_sizes, int n_in,
                              void* d_out, int out_size, void* d_ws, size_t ws_size,
                              hipStream_t stream) {
  // setup_inputs order: t, x, W0, b0, W1, b1, W2, b2, W3, b3
  const float* x  = (const float*)d_in[1];
  const float* W0 = (const float*)d_in[2];
  const float* b0 = (const float*)d_in[3];
  const float* W1 = (const float*)d_in[4];
  const float* b1 = (const float*)d_in[5];
  const float* W2 = (const float*)d_in[6];
  const float* b2 = (const float*)d_in[7];
  const float* W3 = (const float*)d_in[8];
  u16* ws = (u16*)d_ws;
  float* out = (float*)d_out;

  prep_weights<<<136, 256, 0, stream>>>(W0, W1, W2, ws);
  hnn_fused<<<65536 / M_TILE, 512, 0, stream>>>(x, b0, b1, b2, W3, ws, out);
}

// Round 13
// 226.877 us; speedup vs baseline: 1.5203x; 1.0083x over previous
//
#include <hip/hip_runtime.h>
#include <hip/hip_bf16.h>

typedef unsigned short u16;
typedef short s16x8 __attribute__((ext_vector_type(8)));
typedef float f32x4 __attribute__((ext_vector_type(4)));

#define MFMA_BF16(a, b, c) __builtin_amdgcn_mfma_f32_16x16x32_bf16((a), (b), (c), 0, 0, 0)

static constexpr int D_IN   = 64;
static constexpr int H_DIM  = 512;
static constexpr int M_TILE = 64;
static constexpr int AST    = 520;  // LDS row stride (bf16): b128 A-reads conflict-free
static constexpr int XST    = 72;   // LDS row stride for x tile

__device__ __forceinline__ u16 f2bf(float f) {
  unsigned u = __builtin_bit_cast(unsigned, f);
  u += 0x7fffu + ((u >> 16) & 1u);   // RNE
  return (u16)(u >> 16);
}
__device__ __forceinline__ float bfb2f(unsigned bits16) {
  return __builtin_bit_cast(float, bits16 << 16);
}
__device__ __forceinline__ float fast_tanh(float x) {
  float e = __expf(2.0f * x);
  return 1.0f - 2.0f * __builtin_amdgcn_rcpf(e + 1.0f);
}

// LDS-only barrier: drain ds-writes (lgkmcnt) then raw s_barrier, WITHOUT
// the vmcnt(0) drain __syncthreads() emits. In-flight global loads here are
// LOAD_B4 prefetches into private registers -- no cross-wave hazard -- so
// they legally stay in flight across the barrier; the compiler inserts a
// counted vmcnt before their first MFMA use. (-2.5us vs __syncthreads, R10.)
__device__ __forceinline__ void block_sync_lds() {
  asm volatile("s_waitcnt lgkmcnt(0)" ::: "memory");
  __builtin_amdgcn_s_barrier();
  asm volatile("" ::: "memory");
}

// ---- prep: fp32 weights -> bf16, packed in MFMA-B-fragment order ----
__global__ __launch_bounds__(256) void prep_weights(const float* __restrict__ W0,
                                                    const float* __restrict__ W1,
                                                    const float* __restrict__ W2,
                                                    u16* __restrict__ ws) {
  u16* p0f = ws;                       // fwd W0: K=64,  N=512
  u16* p0b = p0f + D_IN * H_DIM;       // bwd W0^T: K=512, N=64
  u16* p1f = p0b + D_IN * H_DIM;
  u16* p1b = p1f + H_DIM * H_DIM;
  u16* p2f = p1b + H_DIM * H_DIM;
  u16* p2b = p2f + H_DIM * H_DIM;

  __shared__ __align__(16) u16 tile[64 * 72];   // 9.0 KB

  int b = blockIdx.x;
  const float* src;
  u16 *dstf, *dstb;
  int rb, cb;
  bool isW0;
  if (b < 64) {
    src = W1; dstf = p1f; dstb = p1b; rb = b >> 3; cb = b & 7; isW0 = false;
  } else if (b < 128) {
    src = W2; dstf = p2f; dstb = p2b; rb = (b - 64) >> 3; cb = (b - 64) & 7; isW0 = false;
  } else {
    src = W0; dstf = p0f; dstb = p0b; rb = 0; cb = b - 128; isW0 = true;
  }

  const int tid = threadIdx.x;

  {
    int r = tid >> 2, cc = (tid & 3) * 16;
    const float4* s4 = (const float4*)(src + (size_t)(rb * 64 + r) * 512 + cb * 64 + cc);
    unsigned pk[8];
    #pragma unroll
    for (int v = 0; v < 4; ++v) {
      float4 f = s4[v];
      pk[v * 2]     = (unsigned)f2bf(f.x) | ((unsigned)f2bf(f.y) << 16);
      pk[v * 2 + 1] = (unsigned)f2bf(f.z) | ((unsigned)f2bf(f.w) << 16);
    }
    uint4* d = (uint4*)(tile + r * 72 + cc);
    d[0] = make_uint4(pk[0], pk[1], pk[2], pk[3]);
    d[1] = make_uint4(pk[4], pk[5], pk[6], pk[7]);
  }
  __syncthreads();

  const int c   = tid >> 6;
  const int kcl = (tid >> 5) & 1;
  const int ls  = (tid * 2) & 63;
  const int q   = ls >> 4;
  const int ln  = ls & 15;

  {
    __align__(16) u16 o[16];
    #pragma unroll
    for (int half = 0; half < 2; ++half)
      #pragma unroll
      for (int j = 0; j < 8; ++j)
        o[half * 8 + j] = tile[(kcl * 32 + q * 8 + j) * 72 + c * 16 + ln + half];
    int ntg   = 4 * cb + c;
    int kc    = 2 * rb + kcl;
    int chunk = isW0 ? (ntg * 2 + kc) : (ntg * 16 + kc);
    u16* dp = dstf + ((size_t)chunk * 64 + ls) * 8;
    *(uint4*)dp       = *(const uint4*)o;
    *(uint4*)(dp + 8) = *(const uint4*)(o + 8);
  }

  {
    const u16* rp = tile + (c * 16 + ln) * 72 + kcl * 32 + q * 8;
    s16x8 r0 = *(const s16x8*)rp;
    s16x8 r1 = *(const s16x8*)(rp + 72);
    int ntg = 4 * rb + c;
    int kc  = 2 * cb + kcl;
    u16* dp = dstb + ((size_t)(ntg * 16 + kc) * 64 + ls) * 8;
    *(s16x8*)dp       = r0;
    *(s16x8*)(dp + 8) = r1;
  }
}

// Load this wave's 4 B-tiles of k-chunk KC straight into VGPRs (BR[4]).
#define LOAD_B4(BP, KC, BR)                                                     \
  {                                                                             \
    const u16* _sr = (BP) + ((size_t)wave << 15) + ((KC) << 9) + lane * 8;      \
    _Pragma("unroll")                                                           \
    for (int s = 0; s < 4; ++s)                                                 \
      (BR)[s] = *(const s16x8*)(_sr + (s << 13));                               \
  }

// 512-wide GEMM K-loop: wave = 64 rows x 64 cols. A from LDS buffer RB
// (b128, conflict-free); B all-register, 2-deep dbuf. No control flow
// inside (R11 lesson: mid-loop branches tip the register cliff -> spill).
#define GEMM512_REG(BP, RB)                                                     \
  {                                                                             \
    _Pragma("unroll") for (int mt = 0; mt < 4; ++mt)                            \
      _Pragma("unroll") for (int nt = 0; nt < 4; ++nt)                          \
        acc[mt][nt] = (f32x4){0.f, 0.f, 0.f, 0.f};                              \
    for (int kc2 = 0; kc2 < 8; ++kc2) {                                         \
      const int e = kc2 * 2;                                                    \
      {                                                                         \
        s16x8 a[4];                                                             \
        _Pragma("unroll")                                                       \
        for (int mt = 0; mt < 4; ++mt)                                          \
          a[mt] = *(const s16x8*)((RB) + (mt * 16 + ln) * AST + e * 32 + q * 8);\
        _Pragma("unroll")                                                       \
        for (int nt = 0; nt < 4; ++nt)                                          \
          _Pragma("unroll")                                                     \
          for (int mt = 0; mt < 4; ++mt)                                        \
            acc[mt][nt] = MFMA_BF16(a[mt], bregA[nt], acc[mt][nt]);             \
        if (kc2 < 7) LOAD_B4(BP, e + 2, bregA);                                 \
      }                                                                         \
      const int o = e + 1;                                                      \
      {                                                                         \
        s16x8 a[4];                                                             \
        _Pragma("unroll")                                                       \
        for (int mt = 0; mt < 4; ++mt)                                          \
          a[mt] = *(const s16x8*)((RB) + (mt * 16 + ln) * AST + o * 32 + q * 8);\
        _Pragma("unroll")                                                       \
        for (int nt = 0; nt < 4; ++nt)                                          \
          _Pragma("unroll")                                                     \
          for (int mt = 0; mt < 4; ++mt)                                        \
            acc[mt][nt] = MFMA_BF16(a[mt], bregB[nt], acc[mt][nt]);             \
        if (kc2 < 7) LOAD_B4(BP, o + 2, bregB);                                 \
      }                                                                         \
    }                                                                           \
  }

// block=512 (8 waves), wave = 64x64 slice. Ping-pong activation LDS,
// lgkmcnt-only barriers, 6 barriers. BEST measured: 159.7us (R10).
// Register-bound at 2 waves/SIMD (R7/8/9/11: any 2x-state, forced-occupancy,
// or mid-loop-branch variant spills); setprio null (R12, clean A/B).
__global__ __launch_bounds__(512, 2) void hnn_fused(
    const float* __restrict__ x,
    const float* __restrict__ bias0,
    const float* __restrict__ bias1,
    const float* __restrict__ bias2,
    const float* __restrict__ W3,
    const u16* __restrict__ ws,
    float* __restrict__ out)
{
  const u16* p0f = ws;
  const u16* p0b = p0f + D_IN * H_DIM;
  const u16* p1f = p0b + D_IN * H_DIM;
  const u16* p1b = p1f + H_DIM * H_DIM;
  const u16* p2f = p1b + H_DIM * H_DIM;
  const u16* p2b = p2f + H_DIM * H_DIM;

  __shared__ __align__(16) u16 xs[M_TILE * XST];     // 9.0 KB
  __shared__ __align__(16) u16 bufA[M_TILE * AST];   // 65.0 KB
  __shared__ __align__(16) u16 bufB[M_TILE * AST];   // 65.0 KB

  const int tid  = threadIdx.x;
  const int wave = tid >> 6;      // 0..7
  const int lane = tid & 63;
  const int ln   = lane & 15;
  const int q    = lane >> 4;
  const int nwb  = wave * 64;     // wave's 64-col slice
  const int row0 = blockIdx.x * M_TILE;

  // ---- stage x tile: 64x64 fp32 -> bf16 LDS (512 thr x 8 elems) ----
  {
    int r = tid >> 3, c = (tid & 7) * 8;
    const float4* src = (const float4*)(x + (size_t)(row0 + r) * D_IN + c);
    float4 f0 = src[0];
    float4 f1 = src[1];
    u16* dst = xs + r * XST + c;
    dst[0] = f2bf(f0.x); dst[1] = f2bf(f0.y); dst[2] = f2bf(f0.z); dst[3] = f2bf(f0.w);
    dst[4] = f2bf(f1.x); dst[5] = f2bf(f1.y); dst[6] = f2bf(f1.z); dst[7] = f2bf(f1.w);
  }
  block_sync_lds();

  f32x4 acc[4][4];
  s16x8 bregA[4], bregB[4];   // register-B double buffer
  unsigned h0p[4][4][2];      // h0 bf16x2-packed, C-layout (for tanh' in bwd)
  unsigned h1p[4][4][2];
  float bias[4];

  // ================ GEMM0: z0 = x @ W0  (K=64, register-B) ================
  #pragma unroll
  for (int nt = 0; nt < 4; ++nt) bias[nt] = bias0[nwb + nt * 16 + ln];
  #pragma unroll
  for (int mt = 0; mt < 4; ++mt)
    #pragma unroll
    for (int nt = 0; nt < 4; ++nt) acc[mt][nt] = (f32x4){0.f, 0.f, 0.f, 0.f};
  {
    const u16* bpw0 = p0f + (wave << 12) + lane * 8;  // (wave*4 ntg) * 2 kc * 512
    #pragma unroll
    for (int kc = 0; kc < 2; ++kc) {
      s16x8 a[4];
      #pragma unroll
      for (int mt = 0; mt < 4; ++mt)
        a[mt] = *(const s16x8*)(xs + (mt * 16 + ln) * XST + kc * 32 + q * 8);
      #pragma unroll
      for (int nt = 0; nt < 4; ++nt) {
        s16x8 b = *(const s16x8*)(bpw0 + (nt << 10) + (kc << 9));
        #pragma unroll
        for (int mt = 0; mt < 4; ++mt)
          acc[mt][nt] = MFMA_BF16(a[mt], b, acc[mt][nt]);
      }
    }
  }
  LOAD_B4(p1f, 0, bregA);   // prefetch GEMM1 kc 0,1; overlaps epilogue VALU
  LOAD_B4(p1f, 1, bregB);
  // epi0: h0 = tanh(z0+b0) -> regs + bufA (first use)
  #pragma unroll
  for (int mt = 0; mt < 4; ++mt)
    #pragma unroll
    for (int nt = 0; nt < 4; ++nt) {
      int col = nwb + nt * 16 + ln;
      u16 u[4];
      #pragma unroll
      for (int r = 0; r < 4; ++r) {
        float th = fast_tanh(acc[mt][nt][r] + bias[nt]);
        u[r] = f2bf(th);
        bufA[(mt * 16 + q * 4 + r) * AST + col] = u[r];
      }
      h0p[mt][nt][0] = (unsigned)u[0] | ((unsigned)u[1] << 16);
      h0p[mt][nt][1] = (unsigned)u[2] | ((unsigned)u[3] << 16);
    }
  block_sync_lds();

  // ================ GEMM1: z1 = h0 @ W1  (reads A, writes B) ================
  #pragma unroll
  for (int nt = 0; nt < 4; ++nt) bias[nt] = bias1[nwb + nt * 16 + ln];
  GEMM512_REG(p1f, bufA);
  LOAD_B4(p2f, 0, bregA);   // prefetch GEMM2
  LOAD_B4(p2f, 1, bregB);
  #pragma unroll
  for (int mt = 0; mt < 4; ++mt)
    #pragma unroll
    for (int nt = 0; nt < 4; ++nt) {
      int col = nwb + nt * 16 + ln;
      u16 u[4];
      #pragma unroll
      for (int r = 0; r < 4; ++r) {
        float th = fast_tanh(acc[mt][nt][r] + bias[nt]);
        u[r] = f2bf(th);
        bufB[(mt * 16 + q * 4 + r) * AST + col] = u[r];
      }
      h1p[mt][nt][0] = (unsigned)u[0] | ((unsigned)u[1] << 16);
      h1p[mt][nt][1] = (unsigned)u[2] | ((unsigned)u[3] << 16);
    }
  block_sync_lds();

  // ================ GEMM2: z2 = h1 @ W2 ; gz2 = W3*(1-h2^2)  (reads B, writes A) ====
  #pragma unroll
  for (int nt = 0; nt < 4; ++nt) bias[nt] = bias2[nwb + nt * 16 + ln];
  float w3v[4];
  #pragma unroll
  for (int nt = 0; nt < 4; ++nt) w3v[nt] = W3[nwb + nt * 16 + ln];
  GEMM512_REG(p2f, bufB);
  LOAD_B4(p2b, 0, bregA);   // prefetch GEMM3
  LOAD_B4(p2b, 1, bregB);
  #pragma unroll
  for (int mt = 0; mt < 4; ++mt)
    #pragma unroll
    for (int nt = 0; nt < 4; ++nt) {
      int col = nwb + nt * 16 + ln;
      #pragma unroll
      for (int r = 0; r < 4; ++r) {
        float th = fast_tanh(acc[mt][nt][r] + bias[nt]);
        float gz = w3v[nt] * (1.0f - th * th);
        bufA[(mt * 16 + q * 4 + r) * AST + col] = f2bf(gz);
      }
    }
  block_sync_lds();

  // ================ GEMM3: g1 = gz2 @ W2^T ; gz1 = g1*(1-h1^2)  (reads A, writes B) ==
  GEMM512_REG(p2b, bufA);
  LOAD_B4(p1b, 0, bregA);   // prefetch GEMM4
  LOAD_B4(p1b, 1, bregB);
  #pragma unroll
  for (int mt = 0; mt < 4; ++mt)
    #pragma unroll
    for (int nt = 0; nt < 4; ++nt) {
      int col = nwb + nt * 16 + ln;
      unsigned pa = h1p[mt][nt][0], pb = h1p[mt][nt][1];
      float hh[4] = { bfb2f(pa & 0xffffu), bfb2f(pa >> 16),
                      bfb2f(pb & 0xffffu), bfb2f(pb >> 16) };
      #pragma unroll
      for (int r = 0; r < 4; ++r) {
        float gz = acc[mt][nt][r] * (1.0f - hh[r] * hh[r]);
        bufB[(mt * 16 + q * 4 + r) * AST + col] = f2bf(gz);
      }
    }
  block_sync_lds();

  // ================ GEMM4: g0 = gz1 @ W1^T ; gz0 = g0*(1-h0^2)  (reads B, writes A) ==
  // No barrier between GEMM4 and epi4: epi4's bufA writes are ordered against
  // GEMM3's bufA reads by the epi3 barrier (ping-pong argument).
  GEMM512_REG(p1b, bufB);
  #pragma unroll
  for (int mt = 0; mt < 4; ++mt)
    #pragma unroll
    for (int nt = 0; nt < 4; ++nt) {
      int col = nwb + nt * 16 + ln;
      unsigned pa = h0p[mt][nt][0], pb = h0p[mt][nt][1];
      float hh[4] = { bfb2f(pa & 0xffffu), bfb2f(pa >> 16),
                      bfb2f(pb & 0xffffu), bfb2f(pb >> 16) };
      #pragma unroll
      for (int r = 0; r < 4; ++r) {
        float gz = acc[mt][nt][r] * (1.0f - hh[r] * hh[r]);
        bufA[(mt * 16 + q * 4 + r) * AST + col] = f2bf(gz);
      }
    }
  block_sync_lds();

  // ================ GEMM5: gradH = gz0 @ W0^T (64x64), symplectic store ======
  {
    f32x4 acc5[2];
    acc5[0] = (f32x4){0.f, 0.f, 0.f, 0.f};
    acc5[1] = (f32x4){0.f, 0.f, 0.f, 0.f};
    const int mt5 = wave & 3;                  // row tile 0..3
    const int nb5 = (wave >> 2) * 32;          // gradH column base (0 or 32)
    const u16* bp5 = p0b + ((wave >> 2) << 14) + lane * 8;  // ntg5*16kc*512
    #pragma unroll 2
    for (int kc = 0; kc < 16; ++kc) {
      s16x8 a = *(const s16x8*)(bufA + (mt5 * 16 + ln) * AST + kc * 32 + q * 8);
      #pragma unroll
      for (int nt = 0; nt < 2; ++nt) {
        s16x8 b = *(const s16x8*)(bp5 + (nt << 13) + (kc << 9));
        acc5[nt] = MFMA_BF16(a, b, acc5[nt]);
      }
    }
    #pragma unroll
    for (int nt = 0; nt < 2; ++nt) {
      int g = nb5 + nt * 16 + ln;                 // gradH column
      int c = (g < 32) ? g + 32 : g - 32;         // out = concat(gradH[:,32:], -gradH[:,:32])
      float s = (g < 32) ? -1.0f : 1.0f;
      #pragma unroll
      for (int r = 0; r < 4; ++r) {
        int grow = row0 + mt5 * 16 + q * 4 + r;
        out[(size_t)grow * 64 + c] = s * acc5[nt][r];
      }
    }
  }
}

extern "C" void kernel_launch(void* const* d_in, const int* in_sizes, int n_in,
                              void* d_out, int out_size, void* d_ws, size_t ws_size,
                              hipStream_t stream) {
  // setup_inputs order: t, x, W0, b0, W1, b1, W2, b2, W3, b3
  const float* x  = (const float*)d_in[1];
  const float* W0 = (const float*)d_in[2];
  const float* b0 = (const float*)d_in[3];
  const float* W1 = (const float*)d_in[4];
  const float* b1 = (const float*)d_in[5];
  const float* W2 = (const float*)d_in[6];
  const float* b2 = (const float*)d_in[7];
  const float* W3 = (const float*)d_in[8];
  u16* ws = (u16*)d_ws;
  float* out = (float*)d_out;

  prep_weights<<<136, 256, 0, stream>>>(W0, W1, W2, ws);
  hnn_fused<<<65536 / M_TILE, 512, 0, stream>>>(x, b0, b1, b2, W3, ws, out);
}